// Round 1
// baseline (255.928 us; speedup 1.0000x reference)
//
#include <hip/hip_runtime.h>
#include <hip/hip_bf16.h>
#include <stdint.h>

#define N_ROWS 16384
#define IN_DIM 768

typedef __bf16 bf16x8 __attribute__((ext_vector_type(8)));
typedef float f32x4 __attribute__((ext_vector_type(4)));

// ---------------- ws layout (bytes) ----------------
// WtT : W_token^T bf16 [128][768]            196608
// WqT : W_qkv^T  bf16 [384][128]              98304
// h   : bf16 [16384][128]                   4194304
// qb  : bf16 [16384][128]  (q * -log2e)     4194304
// kb  : bf16 [16384][128]  (XOR-swizzled)   4194304
// wv  : f32  [16384]  (v . W_fc)              65536
// part: f32  [8][16384]                      524288
#define OFF_WTT  0u
#define OFF_WQT  196608u
#define OFF_H    294912u
#define OFF_QB   4489216u
#define OFF_KB   8683520u
#define OFF_WV   12877824u
#define OFF_PART 12943360u

// ---- kernel 0: cast+transpose weights into k-contiguous bf16 layouts ----
__global__ void prep(const float* __restrict__ Wt, const float* __restrict__ Wq,
                     __bf16* __restrict__ WtT, __bf16* __restrict__ WqT) {
    int t = blockIdx.x * 256 + threadIdx.x;
    if (t < IN_DIM * 128) {            // W_token (768,128) -> WtT[n][k]
        float v = Wt[t];
        int k = t >> 7, n = t & 127;
        WtT[n * IN_DIM + k] = (__bf16)v;
    }
    if (t < 128 * 384) {               // W_qkv (128,384) -> WqT[n][k]
        float v = Wq[t];
        int k = t / 384, n = t % 384;
        WqT[n * 128 + k] = (__bf16)v;
    }
}

// ---- kernel 1: h = bf16(x) @ W_token + b_token  (M=16384,K=768,N=128) ----
__launch_bounds__(256)
__global__ void gemm_h(const float* __restrict__ x, const __bf16* __restrict__ WtT,
                       const float* __restrict__ b_token, __bf16* __restrict__ h) {
    const int wave = threadIdx.x >> 6, lane = threadIdx.x & 63;
    const int n16 = lane & 15, q = lane >> 4;
    const int row0 = blockIdx.x * 64 + wave * 16;
    f32x4 acc[8];
#pragma unroll
    for (int t = 0; t < 8; t++) acc[t] = (f32x4){0, 0, 0, 0};
    const float* ap = x + (size_t)(row0 + n16) * IN_DIM + q * 8;
#pragma unroll
    for (int ks = 0; ks < 24; ks++) {
        float4 a0 = *(const float4*)(ap + ks * 32);
        float4 a1 = *(const float4*)(ap + ks * 32 + 4);
        bf16x8 af;
        af[0] = (__bf16)a0.x; af[1] = (__bf16)a0.y; af[2] = (__bf16)a0.z; af[3] = (__bf16)a0.w;
        af[4] = (__bf16)a1.x; af[5] = (__bf16)a1.y; af[6] = (__bf16)a1.z; af[7] = (__bf16)a1.w;
#pragma unroll
        for (int t = 0; t < 8; t++) {
            bf16x8 bf = *(const bf16x8*)(WtT + (t * 16 + n16) * IN_DIM + ks * 32 + q * 8);
            acc[t] = __builtin_amdgcn_mfma_f32_16x16x32_bf16(af, bf, acc[t], 0, 0, 0);
        }
    }
#pragma unroll
    for (int t = 0; t < 8; t++) {
        int col = t * 16 + n16;
        float bt = b_token[col];
#pragma unroll
        for (int r = 0; r < 4; r++) {
            int row = row0 + q * 4 + r;
            h[row * 128 + col] = (__bf16)(acc[t][r] + bt);
        }
    }
}

// ---- kernel 2: qkv = h @ W_qkv + b_qkv; emit qb(-log2e scaled), kb(swizzled), wv=v.Wfc ----
__launch_bounds__(256)
__global__ void gemm_qkv(const __bf16* __restrict__ h, const __bf16* __restrict__ WqT,
                         const float* __restrict__ b_qkv, const float* __restrict__ W_fc,
                         __bf16* __restrict__ qb, __bf16* __restrict__ kb,
                         float* __restrict__ wv) {
    const int wave = threadIdx.x >> 6, lane = threadIdx.x & 63;
    const int n16 = lane & 15, q = lane >> 4;
    const int row0 = blockIdx.x * 64 + wave * 16;
    bf16x8 af[4];
#pragma unroll
    for (int ks = 0; ks < 4; ks++)
        af[ks] = *(const bf16x8*)(h + (row0 + n16) * 128 + ks * 32 + q * 8);
    f32x4 acc[24];
#pragma unroll
    for (int t = 0; t < 24; t++) acc[t] = (f32x4){0, 0, 0, 0};
#pragma unroll
    for (int t = 0; t < 24; t++) {
#pragma unroll
        for (int ks = 0; ks < 4; ks++) {
            bf16x8 bf = *(const bf16x8*)(WqT + (t * 16 + n16) * 128 + ks * 32 + q * 8);
            acc[t] = __builtin_amdgcn_mfma_f32_16x16x32_bf16(af[ks], bf, acc[t], 0, 0, 0);
        }
    }
    float wacc[4] = {0, 0, 0, 0};
#pragma unroll
    for (int t = 0; t < 24; t++) {
        int col = t * 16 + n16;
        float bq = b_qkv[col];
        float wf = (t >= 16) ? W_fc[col - 256] : 0.0f;
#pragma unroll
        for (int r = 0; r < 4; r++) {
            int row = row0 + q * 4 + r;
            float val = acc[t][r] + bq;
            if (t < 8) {
                qb[row * 128 + col] = (__bf16)(val * -1.44269504088896f);
            } else if (t < 16) {
                int d = col - 128;
                int chunk = (d >> 3) ^ (row & 15);   // XOR swizzle keyed on row%16
                kb[row * 128 + chunk * 8 + (d & 7)] = (__bf16)val;
            } else {
                wacc[r] += val * wf;
            }
        }
    }
#pragma unroll
    for (int r = 0; r < 4; r++) {
        float v = wacc[r];
        v += __shfl_xor(v, 1, 64);
        v += __shfl_xor(v, 2, 64);
        v += __shfl_xor(v, 4, 64);
        v += __shfl_xor(v, 8, 64);
        if (n16 == 0) wv[row0 + q * 4 + r] = v;
    }
}

// ---- kernel 3: partial[sp][i] = sum_{j in slice sp} sigmoid(q_i.k_j) * wv_j ----
// BM=128 rows/block, 8 j-slices, 128-row K chunks staged via global_load_lds.
__launch_bounds__(256, 4)
__global__ void attn(const __bf16* __restrict__ qb, const __bf16* __restrict__ kb,
                     const float* __restrict__ wv, float* __restrict__ partial) {
    __shared__ __bf16 kbuf[128 * 128];
    __shared__ float wbuf[128];
    const int tid = threadIdx.x;
    const int wave = tid >> 6, lane = tid & 63;
    const int n16 = lane & 15, q = lane >> 4;
    const int row0 = blockIdx.x * 128 + wave * 32;
    const int sp = blockIdx.y;
    bf16x8 qf[2][4];
#pragma unroll
    for (int mt = 0; mt < 2; mt++)
#pragma unroll
        for (int ks = 0; ks < 4; ks++)
            qf[mt][ks] = *(const bf16x8*)(qb + (row0 + mt * 16 + n16) * 128 + ks * 32 + q * 8);
    float acc[2][4] = {{0, 0, 0, 0}, {0, 0, 0, 0}};
    for (int jc = 0; jc < 16; jc++) {
        const int jbase = sp * 2048 + jc * 128;
        const char* gsrc = (const char*)kb + (size_t)jbase * 256;
#pragma unroll
        for (int i = 0; i < 8; i++) {
            const int off = wave * 8192 + i * 1024;
            __builtin_amdgcn_global_load_lds(
                (const __attribute__((address_space(1))) void*)(gsrc + off + lane * 16),
                (__attribute__((address_space(3))) void*)((char*)kbuf + off),
                16, 0, 0);
        }
        if (tid < 128) wbuf[tid] = wv[jbase + tid];
        __syncthreads();
#pragma unroll
        for (int t = 0; t < 8; t++) {
            f32x4 s0 = (f32x4){0, 0, 0, 0}, s1 = (f32x4){0, 0, 0, 0};
#pragma unroll
            for (int ks = 0; ks < 4; ks++) {
                const int chunk = (ks * 4 + q) ^ n16;   // undo the global-side swizzle
                bf16x8 bf = *(const bf16x8*)(kbuf + (t * 16 + n16) * 128 + chunk * 8);
                s0 = __builtin_amdgcn_mfma_f32_16x16x32_bf16(qf[0][ks], bf, s0, 0, 0, 0);
                s1 = __builtin_amdgcn_mfma_f32_16x16x32_bf16(qf[1][ks], bf, s1, 0, 0, 0);
            }
            const float wval = wbuf[t * 16 + n16];
#pragma unroll
            for (int r = 0; r < 4; r++) {
                // qb pre-scaled by -log2e: sigmoid(s) = rcp(1 + exp2(s'))
                acc[0][r] += __builtin_amdgcn_rcpf(1.0f + __builtin_amdgcn_exp2f(s0[r])) * wval;
                acc[1][r] += __builtin_amdgcn_rcpf(1.0f + __builtin_amdgcn_exp2f(s1[r])) * wval;
            }
        }
        __syncthreads();
    }
#pragma unroll
    for (int mt = 0; mt < 2; mt++)
#pragma unroll
        for (int r = 0; r < 4; r++) {
            float v = acc[mt][r];
            v += __shfl_xor(v, 1, 64);
            v += __shfl_xor(v, 2, 64);
            v += __shfl_xor(v, 4, 64);
            v += __shfl_xor(v, 8, 64);
            if (n16 == 0) partial[sp * N_ROWS + row0 + mt * 16 + q * 4 + r] = v;
        }
}

// ---- kernel 4: deterministic reduce over 8 slices + b_fc ----
__global__ void reduce_out(const float* __restrict__ partial, const float* __restrict__ b_fc,
                           float* __restrict__ out) {
    int i = blockIdx.x * 256 + threadIdx.x;
    float v = b_fc[0];
#pragma unroll
    for (int s = 0; s < 8; s++) v += partial[s * N_ROWS + i];
    out[i] = v;
}

extern "C" void kernel_launch(void* const* d_in, const int* in_sizes, int n_in,
                              void* d_out, int out_size, void* d_ws, size_t ws_size,
                              hipStream_t stream) {
    const float* x       = (const float*)d_in[0];
    // d_in[1] = decay_value (unused by reference)
    const float* W_token = (const float*)d_in[2];
    const float* b_token = (const float*)d_in[3];
    const float* W_qkv   = (const float*)d_in[4];
    const float* b_qkv   = (const float*)d_in[5];
    const float* W_fc    = (const float*)d_in[6];
    const float* b_fc    = (const float*)d_in[7];
    float* out = (float*)d_out;
    char* ws = (char*)d_ws;

    __bf16* WtT = (__bf16*)(ws + OFF_WTT);
    __bf16* WqT = (__bf16*)(ws + OFF_WQT);
    __bf16* h   = (__bf16*)(ws + OFF_H);
    __bf16* qb  = (__bf16*)(ws + OFF_QB);
    __bf16* kb  = (__bf16*)(ws + OFF_KB);
    float*  wv  = (float*)(ws + OFF_WV);
    float*  part = (float*)(ws + OFF_PART);

    prep<<<384, 256, 0, stream>>>(W_token, W_qkv, WtT, WqT);
    gemm_h<<<256, 256, 0, stream>>>(x, WtT, b_token, h);
    gemm_qkv<<<256, 256, 0, stream>>>(h, WqT, b_qkv, W_fc, qb, kb, wv);
    attn<<<dim3(128, 8), 256, 0, stream>>>(qb, kb, wv, part);
    reduce_out<<<64, 256, 0, stream>>>(part, b_fc, out);
}